// Round 12
// baseline (236.259 us; speedup 1.0000x reference)
//
#include <hip/hip_runtime.h>
#include <hip/hip_bf16.h>

typedef unsigned short u16;
typedef unsigned int u32;
typedef __attribute__((ext_vector_type(8))) short bf16x8;
typedef __attribute__((ext_vector_type(4))) float f32x4;

#define LOG2E 1.44269504088896340736f
#define QSCALE (0.125f * LOG2E)
#define DEFER_THR 8.0f

#define WAITCNT_VM(N) asm volatile("s_waitcnt vmcnt(" #N ")" ::: "memory")

// ---------- helpers ----------

__device__ inline u16 f2bf(float f) {            // RNE
  union { float f; u32 u; } v; v.f = f;
  u32 r = v.u + 0x7fffu + ((v.u >> 16) & 1u);
  return (u16)(r >> 16);
}

__device__ inline void gload_lds16(const void* g, void* l) {
  __builtin_amdgcn_global_load_lds(
      (const __attribute__((address_space(1))) u32*)g,
      (__attribute__((address_space(3))) u32*)l, 16, 0, 0);
}

// DPP move within 16-lane rows (row_ror:N = 0x120+N)
template<int CTRL>
__device__ inline float dppmov(float x) {
  int i = __builtin_bit_cast(int, x);
  int r = __builtin_amdgcn_update_dpp(i, i, CTRL, 0xf, 0xf, false);
  return __builtin_bit_cast(float, r);
}
__device__ inline float rowmax16(float v) {
  v = fmaxf(v, dppmov<0x128>(v));
  v = fmaxf(v, dppmov<0x124>(v));
  v = fmaxf(v, dppmov<0x122>(v));
  v = fmaxf(v, dppmov<0x121>(v));
  return v;
}
__device__ inline float rowsum16(float v) {
  v += dppmov<0x128>(v);
  v += dppmov<0x124>(v);
  v += dppmov<0x122>(v);
  v += dppmov<0x121>(v);
  return v;
}

// ---------- fp32 -> bf16 conversion ----------

__global__ void cvt_multi(const float4* __restrict__ s0, const float4* __restrict__ s1,
                          const float4* __restrict__ s2, const float4* __restrict__ s3,
                          ushort4* __restrict__ d0, ushort4* __restrict__ d1,
                          ushort4* __restrict__ d2, ushort4* __restrict__ d3, int n4) {
  const float4* s; ushort4* d;
  switch (blockIdx.y) {
    case 0: s = s0; d = d0; break;
    case 1: s = s1; d = d1; break;
    case 2: s = s2; d = d2; break;
    default: s = s3; d = d3; break;
  }
  int stride = gridDim.x * blockDim.x;
  for (int i = blockIdx.x * blockDim.x + threadIdx.x; i < n4; i += stride) {
    float4 v = s[i];
    ushort4 o;
    o.x = f2bf(v.x); o.y = f2bf(v.y); o.z = f2bf(v.z); o.w = f2bf(v.w);
    d[i] = o;
  }
}

// ---------- per-(b, kv-tile) padding-mask OR flags ----------

__global__ void mask_flags(const unsigned char* __restrict__ mask,
                           unsigned char* __restrict__ flags) {
  int t = threadIdx.x;   // 0..127
  if (t >= 128) return;
  const uint4* p = (const uint4*)(mask + (size_t)t * 64);
  uint4 a = p[0], b = p[1], c = p[2], d = p[3];
  u32 v = a.x | a.y | a.z | a.w | b.x | b.y | b.z | b.w |
          c.x | c.y | c.z | c.w | d.x | d.y | d.z | d.w;
  flags[t] = v ? 1 : 0;
}

// ---------- fused Q/K/V projection (r11: 3-buffer counted vmcnt, frozen) ----------

__global__ __launch_bounds__(256) void gemm_qkv(
    const u16* __restrict__ Aq, const u16* __restrict__ Ak, const u16* __restrict__ Av,
    const u16* __restrict__ Wqb, const u16* __restrict__ Wkb, const u16* __restrict__ Wvb,
    const float* __restrict__ bqp, const float* __restrict__ bkp, const float* __restrict__ bvp,
    u16* __restrict__ Qh, u16* __restrict__ Kh, u16* __restrict__ Vt,
    int M, int N, int K) {
  constexpr int BK = 32;
  __shared__ u16 sA[3][128 * BK];
  __shared__ u16 sB[3][128 * BK];

  // XCD-chunked bijective swizzle (nwg = 1536, %8==0)
  const int hw = blockIdx.z * 512 + blockIdx.y * 8 + blockIdx.x;
  const int lg = (hw & 7) * 192 + (hw >> 3);
  const int z = lg / 512;
  const int rem = lg - z * 512;
  const int m0 = (rem >> 3) * 128;
  const int n0 = (rem & 7) * 128;

  const u16* A  = (z == 0) ? Aq : (z == 1) ? Ak : Av;
  const u16* Bt = (z == 0) ? Wqb : (z == 1) ? Wkb : Wvb;
  const float* bias = (z == 0) ? bqp : (z == 1) ? bkp : bvp;

  const int tid = threadIdx.x;
  const int lane = tid & 63;
  const int wave = tid >> 6;
  const int g = lane >> 4;
  const int r = lane & 15;
  const int wr = wave >> 1, wc = wave & 1;

  f32x4 acc[4][4] = {};

  auto stage = [&](int buf, int kt) {   // exactly 4 gload_lds per thread
    const int k0 = kt * BK;
#pragma unroll
    for (int i = 0; i < 2; ++i) {
      int c = tid + i * 256;
      int row = c >> 2, cc = c & 3;
      gload_lds16(A + (size_t)(m0 + row) * K + k0 + cc * 8, &sA[buf][0] + c * 8);
    }
#pragma unroll
    for (int i = 0; i < 2; ++i) {
      int c = tid + i * 256;
      int row = c >> 2, cc = c & 3;
      gload_lds16(Bt + (size_t)(n0 + row) * K + k0 + cc * 8, &sB[buf][0] + c * 8);
    }
  };

  auto compute = [&](int buf) {
    const u16* a_base = &sA[buf][0];
    const u16* b_base = &sB[buf][0];
    bf16x8 avf[4], bvf[4];
#pragma unroll
    for (int i = 0; i < 4; ++i) {
      avf[i] = *(const bf16x8*)(a_base + (wr * 64 + i * 16 + r) * BK + g * 8);
      bvf[i] = *(const bf16x8*)(b_base + (wc * 64 + i * 16 + r) * BK + g * 8);
    }
#pragma unroll
    for (int i = 0; i < 4; ++i)
#pragma unroll
      for (int j = 0; j < 4; ++j)
        acc[i][j] = __builtin_amdgcn_mfma_f32_16x16x32_bf16(avf[i], bvf[j], acc[i][j], 0, 0, 0);
  };

  const int NT = K / BK;   // 32

  stage(0, 0);
  stage(1, 1);

  int cur = 0;
  for (int kt = 0; kt < NT; ++kt) {
    if (kt + 1 < NT) { WAITCNT_VM(4); } else { WAITCNT_VM(0); }
    __builtin_amdgcn_s_barrier();
    __builtin_amdgcn_sched_barrier(0);
    if (kt + 2 < NT) {
      int s2 = cur + 2; if (s2 >= 3) s2 -= 3;
      stage(s2, kt + 2);
    }
    compute(cur);
    cur = (cur == 2) ? 0 : cur + 1;
  }

#pragma unroll
  for (int i = 0; i < 4; ++i) {
    int rowb = m0 + wr * 64 + i * 16 + g * 4;
#pragma unroll
    for (int j = 0; j < 4; ++j) {
      int col = n0 + wc * 64 + j * 16 + r;
      float bv = bias[col];
#pragma unroll
      for (int q = 0; q < 4; ++q) {
        int row = rowb + q;
        float v = acc[i][j][q] + bv;
        int b = row >> 10, t = row & 1023, h = col >> 6, d = col & 63;
        if (z == 0) {
          Qh[((((size_t)b * 16 + h) << 10) + t) * 64 + d] = f2bf(v * QSCALE);
        } else if (z == 1) {
          Kh[((((size_t)b * 16 + h) << 10) + t) * 64 + d] = f2bf(v);
        } else {
          Vt[(((size_t)b * 16 + h) * 64 + d) * 1024 + t] = f2bf(v);
        }
      }
    }
  }
}

// ---------- O-projection GEMM (r9 2-phase + XCD swizzle, frozen) ----------

__global__ __launch_bounds__(256) void gemm_o(
    const u16* __restrict__ A, const u16* __restrict__ Bt,
    const float* __restrict__ bias, float* __restrict__ Cout,
    int M, int N, int K) {
  constexpr int BK = 32;
  __shared__ u16 sA[2][128 * BK];
  __shared__ u16 sB[2][128 * BK];

  const int hw = blockIdx.y * 8 + blockIdx.x;   // grid (8,64) = 512
  const int lg = (hw & 7) * 64 + (hw >> 3);
  const int m0 = (lg >> 3) * 128;
  const int n0 = (lg & 7) * 128;

  const int tid = threadIdx.x;
  const int lane = tid & 63;
  const int wave = tid >> 6;
  const int g = lane >> 4;
  const int r = lane & 15;
  const int wr = wave >> 1, wc = wave & 1;

  f32x4 acc[4][4] = {};

  auto stage = [&](int buf, int kt) {
    const int k0 = kt * BK;
#pragma unroll
    for (int i = 0; i < 2; ++i) {
      int c = tid + i * 256;
      int row = c >> 2, cc = c & 3;
      gload_lds16(A + (size_t)(m0 + row) * K + k0 + cc * 8, &sA[buf][0] + c * 8);
    }
#pragma unroll
    for (int i = 0; i < 2; ++i) {
      int c = tid + i * 256;
      int row = c >> 2, cc = c & 3;
      gload_lds16(Bt + (size_t)(n0 + row) * K + k0 + cc * 8, &sB[buf][0] + c * 8);
    }
  };

  stage(0, 0);
  const int NT = K / BK;
  for (int kt = 0; kt < NT; ++kt) {
    __syncthreads();
    if (kt + 1 < NT) stage((kt + 1) & 1, kt + 1);
    const u16* a_base = &sA[kt & 1][0];
    const u16* b_base = &sB[kt & 1][0];
    bf16x8 avf[4], bvf[4];
#pragma unroll
    for (int i = 0; i < 4; ++i) {
      avf[i] = *(const bf16x8*)(a_base + (wr * 64 + i * 16 + r) * BK + g * 8);
      bvf[i] = *(const bf16x8*)(b_base + (wc * 64 + i * 16 + r) * BK + g * 8);
    }
#pragma unroll
    for (int i = 0; i < 4; ++i)
#pragma unroll
      for (int j = 0; j < 4; ++j)
        acc[i][j] = __builtin_amdgcn_mfma_f32_16x16x32_bf16(avf[i], bvf[j], acc[i][j], 0, 0, 0);
  }

#pragma unroll
  for (int i = 0; i < 4; ++i) {
    int rowb = m0 + wr * 64 + i * 16 + g * 4;
#pragma unroll
    for (int j = 0; j < 4; ++j) {
      int col = n0 + wc * 64 + j * 16 + r;
      float bv = bias[col];
#pragma unroll
      for (int q = 0; q < 4; ++q) {
        int row = rowb + q;
        Cout[(size_t)row * N + col] = acc[i][j][q] + bv;
      }
    }
  }
}

// ---------- flash attention: 8 waves / 256 q-rows per block ----------
// Per staged K/V tile, 2x the MFMA per barrier vs r9; K/V staging traffic and
// barrier count per unit work halve. Grid (128 bh, 4 qtslot), LPT (qt=3 first).
// Wave w owns q-rows [qt*256 + w*32, +32). Inner math identical to r9
// (DPP softmax, exp2 domain, defer-max, setprio, XOR-swizzled tiles).

__global__ __launch_bounds__(512) void attn_fwd(
    const u16* __restrict__ Qh, const u16* __restrict__ Kh,
    const u16* __restrict__ Vt, const unsigned char* __restrict__ mask,
    const unsigned char* __restrict__ padflags,
    u16* __restrict__ O) {
  constexpr int S = 1024, DH = 64;
  __shared__ u16 sK[2][64 * 64];
  __shared__ u16 sV[2][64 * 64];
  __shared__ u16 sP[8][16 * 64];

  const int tid = threadIdx.x, lane = tid & 63, wave = tid >> 6;  // wave 0..7
  const int g = lane >> 4, r = lane & 15;
  const int bh = blockIdx.x;
  const int qt = (int)gridDim.y - 1 - (int)blockIdx.y;   // LPT: heavy first
  const int b = bh >> 4, h = bh & 15;
  const int qw = qt * 256 + wave * 32;

  bf16x8 qf[2][2];
#pragma unroll
  for (int u = 0; u < 2; ++u) {
    const u16* Qb = Qh + ((size_t)bh * S + qw + u * 16 + r) * DH;
    qf[u][0] = *(const bf16x8*)(Qb + g * 8);
    qf[u][1] = *(const bf16x8*)(Qb + 32 + g * 8);
  }

  f32x4 acc[2][4] = {};
  float mrun[2][4], lrun[2][4];
#pragma unroll
  for (int u = 0; u < 2; ++u)
#pragma unroll
    for (int i = 0; i < 4; ++i) { mrun[u][i] = -INFINITY; lrun[u][i] = 0.f; }

  auto stage = [&](int buf, int kvt) {   // 512 threads: 1 chunk each per tile
    const int s0k = kvt * 64;
    int c = tid;
    int row = c >> 3;
    int cc = (c & 7) ^ (row & 7);
    gload_lds16(Kh + ((size_t)bh * S + s0k + row) * DH + cc * 8, &sK[buf][0] + c * 8);
    gload_lds16(Vt + ((size_t)bh * DH + row) * S + s0k + cc * 8, &sV[buf][0] + c * 8);
  };

  const int NT = 4 * (qt + 1);
  stage(0, 0);
  for (int kvt = 0; kvt < NT; ++kvt) {
    __syncthreads();
    if (kvt + 1 < NT) stage((kvt + 1) & 1, kvt + 1);
    const int cur = kvt & 1;
    const int s0 = kvt * 64;
    const bool pad = padflags[b * 16 + (s0 >> 6)] != 0;
    const u16* Kb = &sK[cur][0];
    const u16* Vb = &sV[cur][0];
    u16* Pw = &sP[wave][0];

#pragma unroll
    for (int u = 0; u < 2; ++u) {
      const int qg = qw + u * 16;
      if (s0 > qg + 15) continue;
      const bool diag = (s0 + 63 > qg);

      f32x4 sc[4] = {};
      __builtin_amdgcn_s_setprio(1);
#pragma unroll
      for (int ss = 0; ss < 4; ++ss) {
#pragma unroll
        for (int kc = 0; kc < 2; ++kc) {
          int krow = ss * 16 + r;
          int byteoff = krow * 128 + kc * 64 + g * 16;
          bf16x8 kf = *(const bf16x8*)((const char*)Kb + (byteoff ^ ((krow & 7) << 4)));
          sc[ss] = __builtin_amdgcn_mfma_f32_16x16x32_bf16(qf[u][kc], kf, sc[ss], 0, 0, 0);
        }
      }
      __builtin_amdgcn_s_setprio(0);

      float sv[4][4];
      float pmax[4] = {-INFINITY, -INFINITY, -INFINITY, -INFINITY};
#pragma unroll
      for (int ss = 0; ss < 4; ++ss) {
        float padd = 0.f;
        if (pad) {
          int s_g = s0 + ss * 16 + r;
          if (mask[(size_t)b * S + s_g]) padd = -INFINITY;
        }
#pragma unroll
        for (int reg = 0; reg < 4; ++reg) {
          float v = sc[ss][reg] + padd;
          if (diag) {
            int s_g = s0 + ss * 16 + r;
            int q_g = qg + g * 4 + reg;
            if (s_g > q_g) v = -INFINITY;
          }
          sv[ss][reg] = v;
          pmax[reg] = fmaxf(pmax[reg], v);
        }
      }

      float tm[4];
#pragma unroll
      for (int reg = 0; reg < 4; ++reg) tm[reg] = rowmax16(pmax[reg]);
      float dmax = fmaxf(fmaxf(tm[0] - mrun[u][0], tm[1] - mrun[u][1]),
                         fmaxf(tm[2] - mrun[u][2], tm[3] - mrun[u][3]));
      if (__any(dmax > DEFER_THR)) {
#pragma unroll
        for (int reg = 0; reg < 4; ++reg) {
          float newm = fmaxf(mrun[u][reg], tm[reg]);
          float alpha = (newm == -INFINITY) ? 1.f : exp2f(mrun[u][reg] - newm);
          mrun[u][reg] = newm;
          float rs = 0.f;
#pragma unroll
          for (int ss = 0; ss < 4; ++ss) {
            float p = (newm == -INFINITY) ? 0.f : exp2f(sv[ss][reg] - newm);
            sv[ss][reg] = p;
            rs += p;
          }
          rs = rowsum16(rs);
          lrun[u][reg] = lrun[u][reg] * alpha + rs;
#pragma unroll
          for (int df = 0; df < 4; ++df) acc[u][df][reg] *= alpha;
        }
      } else {
#pragma unroll
        for (int reg = 0; reg < 4; ++reg) {
          float m = mrun[u][reg];
          float rs = 0.f;
#pragma unroll
          for (int ss = 0; ss < 4; ++ss) {
            float p = (m == -INFINITY) ? 0.f : exp2f(sv[ss][reg] - m);
            sv[ss][reg] = p;
            rs += p;
          }
          rs = rowsum16(rs);
          lrun[u][reg] += rs;
        }
      }

#pragma unroll
      for (int ss = 0; ss < 4; ++ss) {
#pragma unroll
        for (int reg = 0; reg < 4; ++reg) {
          int qrow = g * 4 + reg;
          int byteoff = qrow * 128 + (ss * 16 + r) * 2;
          u32 bits = __builtin_bit_cast(u32, sv[ss][reg]);
          *(u16*)((char*)Pw + (byteoff ^ ((qrow & 7) << 4))) = (u16)(bits >> 16);
        }
      }

      __builtin_amdgcn_s_setprio(1);
#pragma unroll
      for (int sc2 = 0; sc2 < 2; ++sc2) {
        int pbyte = r * 128 + sc2 * 64 + g * 16;
        bf16x8 pf = *(const bf16x8*)((const char*)Pw + (pbyte ^ ((r & 7) << 4)));
#pragma unroll
        for (int df = 0; df < 4; ++df) {
          int vrow = df * 16 + r;
          int vbyte = vrow * 128 + sc2 * 64 + g * 16;
          bf16x8 vf = *(const bf16x8*)((const char*)Vb + (vbyte ^ ((vrow & 7) << 4)));
          acc[u][df] = __builtin_amdgcn_mfma_f32_16x16x32_bf16(pf, vf, acc[u][df], 0, 0, 0);
        }
      }
      __builtin_amdgcn_s_setprio(0);
    }
  }

#pragma unroll
  for (int u = 0; u < 2; ++u) {
#pragma unroll
    for (int reg = 0; reg < 4; ++reg) {
      float l = lrun[u][reg];
      float inv = (l > 0.f) ? 1.f / l : 0.f;
      int t = qw + u * 16 + g * 4 + reg;
#pragma unroll
      for (int df = 0; df < 4; ++df) {
        float vo = acc[u][df][reg] * inv;
        O[((size_t)b * 1024 + t) * 1024 + h * 64 + df * 16 + r] = f2bf(vo);
      }
    }
  }
}

// ---------- launch ----------

extern "C" void kernel_launch(void* const* d_in, const int* in_sizes, int n_in,
                              void* d_out, int out_size, void* d_ws, size_t ws_size,
                              hipStream_t stream) {
  const float* q  = (const float*)d_in[0];
  const float* k  = (const float*)d_in[1];
  const float* v  = (const float*)d_in[2];
  const unsigned char* mask = (const unsigned char*)d_in[3];
  const float* Wq = (const float*)d_in[4];
  const float* bq = (const float*)d_in[5];
  const float* Wk = (const float*)d_in[6];
  const float* bk = (const float*)d_in[7];
  const float* Wv = (const float*)d_in[8];
  const float* bv = (const float*)d_in[9];
  const float* Wo = (const float*)d_in[10];
  const float* bo = (const float*)d_in[11];

  const int M = 8192, N = 1024, K = 1024;
  const size_t MB = 1u << 20;
  char* ws = (char*)d_ws;

  u16* Aq   = (u16*)(ws);                 // 16MB, reused as AttO after QKV GEMM
  u16* Ak   = (u16*)(ws + 16 * MB);
  u16* Av   = (u16*)(ws + 32 * MB);
  u16* Qh   = (u16*)(ws + 48 * MB);
  u16* Kh   = (u16*)(ws + 64 * MB);
  u16* Vt   = (u16*)(ws + 80 * MB);
  u16* Wqb  = (u16*)(ws + 96 * MB);
  u16* Wkb  = Wqb + (1u << 20);
  u16* Wvb  = Wkb + (1u << 20);
  u16* Wob  = Wvb + (1u << 20);
  unsigned char* flags = (unsigned char*)(ws + 104 * MB);
  u16* AttO = Aq;

  cvt_multi<<<dim3(1024, 3), 256, 0, stream>>>(
      (const float4*)q, (const float4*)k, (const float4*)v, (const float4*)q,
      (ushort4*)Aq, (ushort4*)Ak, (ushort4*)Av, (ushort4*)Aq, (M * K) / 4);
  cvt_multi<<<dim3(256, 4), 256, 0, stream>>>(
      (const float4*)Wq, (const float4*)Wk, (const float4*)Wv, (const float4*)Wo,
      (ushort4*)Wqb, (ushort4*)Wkb, (ushort4*)Wvb, (ushort4*)Wob, (N * K) / 4);
  mask_flags<<<1, 128, 0, stream>>>(mask, flags);

  gemm_qkv<<<dim3(8, 64, 3), 256, 0, stream>>>(
      Aq, Ak, Av, Wqb, Wkb, Wvb, bq, bk, bv, Qh, Kh, Vt, M, N, K);

  attn_fwd<<<dim3(128, 4), 512, 0, stream>>>(Qh, Kh, Vt, mask, flags, AttO);

  gemm_o<<<dim3(8, 64), 256, 0, stream>>>(
      AttO, Wob, bo, (float*)d_out, M, N, K);
}

// Round 13
// 225.858 us; speedup vs baseline: 1.0460x; 1.0460x over previous
//
#include <hip/hip_runtime.h>
#include <hip/hip_bf16.h>

typedef unsigned short u16;
typedef unsigned int u32;
typedef __attribute__((ext_vector_type(8))) short bf16x8;
typedef __attribute__((ext_vector_type(4))) float f32x4;

#define LOG2E 1.44269504088896340736f
#define QSCALE (0.125f * LOG2E)
#define DEFER_THR 8.0f

// ---------- helpers ----------

__device__ inline u16 f2bf(float f) {            // RNE
  union { float f; u32 u; } v; v.f = f;
  u32 r = v.u + 0x7fffu + ((v.u >> 16) & 1u);
  return (u16)(r >> 16);
}

__device__ inline void gload_lds16(const void* g, void* l) {
  __builtin_amdgcn_global_load_lds(
      (const __attribute__((address_space(1))) u32*)g,
      (__attribute__((address_space(3))) u32*)l, 16, 0, 0);
}

// DPP move within 16-lane rows (row_ror:N = 0x120+N)
template<int CTRL>
__device__ inline float dppmov(float x) {
  int i = __builtin_bit_cast(int, x);
  int r = __builtin_amdgcn_update_dpp(i, i, CTRL, 0xf, 0xf, false);
  return __builtin_bit_cast(float, r);
}
__device__ inline float rowmax16(float v) {
  v = fmaxf(v, dppmov<0x128>(v));
  v = fmaxf(v, dppmov<0x124>(v));
  v = fmaxf(v, dppmov<0x122>(v));
  v = fmaxf(v, dppmov<0x121>(v));
  return v;
}
__device__ inline float rowsum16(float v) {
  v += dppmov<0x128>(v);
  v += dppmov<0x124>(v);
  v += dppmov<0x122>(v);
  v += dppmov<0x121>(v);
  return v;
}

// ---------- fp32 -> bf16: all 7 tensors in ONE dispatch ----------
// grid (1024, 7): y=0..2 -> q,k,v (n4=2097152, 8 elems/thread);
// y=3..6 -> Wq,Wk,Wv,Wo (n4=262144, exactly 1 elem/thread).

__global__ void cvt_all(const float4* __restrict__ q, const float4* __restrict__ k,
                        const float4* __restrict__ v,
                        const float4* __restrict__ Wq, const float4* __restrict__ Wk,
                        const float4* __restrict__ Wv, const float4* __restrict__ Wo,
                        ushort4* __restrict__ dq, ushort4* __restrict__ dk,
                        ushort4* __restrict__ dv,
                        ushort4* __restrict__ dWq, ushort4* __restrict__ dWk,
                        ushort4* __restrict__ dWv, ushort4* __restrict__ dWo,
                        int n4A, int n4W) {
  const float4* s; ushort4* d; int n4;
  switch (blockIdx.y) {
    case 0: s = q;  d = dq;  n4 = n4A; break;
    case 1: s = k;  d = dk;  n4 = n4A; break;
    case 2: s = v;  d = dv;  n4 = n4A; break;
    case 3: s = Wq; d = dWq; n4 = n4W; break;
    case 4: s = Wk; d = dWk; n4 = n4W; break;
    case 5: s = Wv; d = dWv; n4 = n4W; break;
    default: s = Wo; d = dWo; n4 = n4W; break;
  }
  int stride = gridDim.x * blockDim.x;
  for (int i = blockIdx.x * blockDim.x + threadIdx.x; i < n4; i += stride) {
    float4 x = s[i];
    ushort4 o;
    o.x = f2bf(x.x); o.y = f2bf(x.y); o.z = f2bf(x.z); o.w = f2bf(x.w);
    d[i] = o;
  }
}

// ---------- per-(b, kv-tile) padding-mask OR flags ----------

__global__ void mask_flags(const unsigned char* __restrict__ mask,
                           unsigned char* __restrict__ flags) {
  int t = threadIdx.x;   // 0..127
  if (t >= 128) return;
  const uint4* p = (const uint4*)(mask + (size_t)t * 64);
  uint4 a = p[0], b = p[1], c = p[2], d = p[3];
  u32 v = a.x | a.y | a.z | a.w | b.x | b.y | b.z | b.w |
          c.x | c.y | c.z | c.w | d.x | d.y | d.z | d.w;
  flags[t] = v ? 1 : 0;
}

// ---------- fused Q/K/V projection (r9 best: 2-phase, 2-buffer, XCD swizzle) ----------

__global__ __launch_bounds__(256) void gemm_qkv(
    const u16* __restrict__ Aq, const u16* __restrict__ Ak, const u16* __restrict__ Av,
    const u16* __restrict__ Wqb, const u16* __restrict__ Wkb, const u16* __restrict__ Wvb,
    const float* __restrict__ bqp, const float* __restrict__ bkp, const float* __restrict__ bvp,
    u16* __restrict__ Qh, u16* __restrict__ Kh, u16* __restrict__ Vt,
    int M, int N, int K) {
  constexpr int BK = 32;
  __shared__ u16 sA[2][128 * BK];
  __shared__ u16 sB[2][128 * BK];

  // XCD-chunked bijective swizzle (nwg = 1536, %8==0)
  const int hw = blockIdx.z * 512 + blockIdx.y * 8 + blockIdx.x;
  const int lg = (hw & 7) * 192 + (hw >> 3);
  const int z = lg / 512;
  const int rem = lg - z * 512;
  const int m0 = (rem >> 3) * 128;
  const int n0 = (rem & 7) * 128;

  const u16* A  = (z == 0) ? Aq : (z == 1) ? Ak : Av;
  const u16* Bt = (z == 0) ? Wqb : (z == 1) ? Wkb : Wvb;
  const float* bias = (z == 0) ? bqp : (z == 1) ? bkp : bvp;

  const int tid = threadIdx.x;
  const int lane = tid & 63;
  const int wave = tid >> 6;
  const int g = lane >> 4;
  const int r = lane & 15;
  const int wr = wave >> 1, wc = wave & 1;

  f32x4 acc[4][4] = {};

  auto stage = [&](int buf, int kt) {
    const int k0 = kt * BK;
#pragma unroll
    for (int i = 0; i < 2; ++i) {
      int c = tid + i * 256;
      int row = c >> 2, cc = c & 3;
      gload_lds16(A + (size_t)(m0 + row) * K + k0 + cc * 8, &sA[buf][0] + c * 8);
    }
#pragma unroll
    for (int i = 0; i < 2; ++i) {
      int c = tid + i * 256;
      int row = c >> 2, cc = c & 3;
      gload_lds16(Bt + (size_t)(n0 + row) * K + k0 + cc * 8, &sB[buf][0] + c * 8);
    }
  };

  stage(0, 0);
  const int NT = K / BK;
  for (int kt = 0; kt < NT; ++kt) {
    __syncthreads();
    if (kt + 1 < NT) stage((kt + 1) & 1, kt + 1);
    const u16* a_base = &sA[kt & 1][0];
    const u16* b_base = &sB[kt & 1][0];
    bf16x8 avf[4], bvf[4];
#pragma unroll
    for (int i = 0; i < 4; ++i) {
      avf[i] = *(const bf16x8*)(a_base + (wr * 64 + i * 16 + r) * BK + g * 8);
      bvf[i] = *(const bf16x8*)(b_base + (wc * 64 + i * 16 + r) * BK + g * 8);
    }
#pragma unroll
    for (int i = 0; i < 4; ++i)
#pragma unroll
      for (int j = 0; j < 4; ++j)
        acc[i][j] = __builtin_amdgcn_mfma_f32_16x16x32_bf16(avf[i], bvf[j], acc[i][j], 0, 0, 0);
  }

#pragma unroll
  for (int i = 0; i < 4; ++i) {
    int rowb = m0 + wr * 64 + i * 16 + g * 4;
#pragma unroll
    for (int j = 0; j < 4; ++j) {
      int col = n0 + wc * 64 + j * 16 + r;
      float bv = bias[col];
#pragma unroll
      for (int q = 0; q < 4; ++q) {
        int row = rowb + q;
        float v = acc[i][j][q] + bv;
        int b = row >> 10, t = row & 1023, h = col >> 6, d = col & 63;
        if (z == 0) {
          Qh[((((size_t)b * 16 + h) << 10) + t) * 64 + d] = f2bf(v * QSCALE);
        } else if (z == 1) {
          Kh[((((size_t)b * 16 + h) << 10) + t) * 64 + d] = f2bf(v);
        } else {
          Vt[(((size_t)b * 16 + h) * 64 + d) * 1024 + t] = f2bf(v);
        }
      }
    }
  }
}

// ---------- O-projection GEMM (r9: 2-phase + XCD swizzle) ----------

__global__ __launch_bounds__(256) void gemm_o(
    const u16* __restrict__ A, const u16* __restrict__ Bt,
    const float* __restrict__ bias, float* __restrict__ Cout,
    int M, int N, int K) {
  constexpr int BK = 32;
  __shared__ u16 sA[2][128 * BK];
  __shared__ u16 sB[2][128 * BK];

  const int hw = blockIdx.y * 8 + blockIdx.x;   // grid (8,64) = 512
  const int lg = (hw & 7) * 64 + (hw >> 3);
  const int m0 = (lg >> 3) * 128;
  const int n0 = (lg & 7) * 128;

  const int tid = threadIdx.x;
  const int lane = tid & 63;
  const int wave = tid >> 6;
  const int g = lane >> 4;
  const int r = lane & 15;
  const int wr = wave >> 1, wc = wave & 1;

  f32x4 acc[4][4] = {};

  auto stage = [&](int buf, int kt) {
    const int k0 = kt * BK;
#pragma unroll
    for (int i = 0; i < 2; ++i) {
      int c = tid + i * 256;
      int row = c >> 2, cc = c & 3;
      gload_lds16(A + (size_t)(m0 + row) * K + k0 + cc * 8, &sA[buf][0] + c * 8);
    }
#pragma unroll
    for (int i = 0; i < 2; ++i) {
      int c = tid + i * 256;
      int row = c >> 2, cc = c & 3;
      gload_lds16(Bt + (size_t)(n0 + row) * K + k0 + cc * 8, &sB[buf][0] + c * 8);
    }
  };

  stage(0, 0);
  const int NT = K / BK;
  for (int kt = 0; kt < NT; ++kt) {
    __syncthreads();
    if (kt + 1 < NT) stage((kt + 1) & 1, kt + 1);
    const u16* a_base = &sA[kt & 1][0];
    const u16* b_base = &sB[kt & 1][0];
    bf16x8 avf[4], bvf[4];
#pragma unroll
    for (int i = 0; i < 4; ++i) {
      avf[i] = *(const bf16x8*)(a_base + (wr * 64 + i * 16 + r) * BK + g * 8);
      bvf[i] = *(const bf16x8*)(b_base + (wc * 64 + i * 16 + r) * BK + g * 8);
    }
#pragma unroll
    for (int i = 0; i < 4; ++i)
#pragma unroll
      for (int j = 0; j < 4; ++j)
        acc[i][j] = __builtin_amdgcn_mfma_f32_16x16x32_bf16(avf[i], bvf[j], acc[i][j], 0, 0, 0);
  }

#pragma unroll
  for (int i = 0; i < 4; ++i) {
    int rowb = m0 + wr * 64 + i * 16 + g * 4;
#pragma unroll
    for (int j = 0; j < 4; ++j) {
      int col = n0 + wc * 64 + j * 16 + r;
      float bv = bias[col];
#pragma unroll
      for (int q = 0; q < 4; ++q) {
        int row = rowb + q;
        Cout[(size_t)row * N + col] = acc[i][j][q] + bv;
      }
    }
  }
}

// ---------- flash attention (r9 best: 4 waves, grid 128x8, defer-max, setprio) ----------

__global__ __launch_bounds__(256) void attn_fwd(
    const u16* __restrict__ Qh, const u16* __restrict__ Kh,
    const u16* __restrict__ Vt, const unsigned char* __restrict__ mask,
    const unsigned char* __restrict__ padflags,
    u16* __restrict__ O) {
  constexpr int S = 1024, DH = 64;
  __shared__ u16 sK[2][64 * 64];
  __shared__ u16 sV[2][64 * 64];
  __shared__ u16 sP[4][16 * 64];

  const int tid = threadIdx.x, lane = tid & 63, wave = tid >> 6;
  const int g = lane >> 4, r = lane & 15;
  const int bh = blockIdx.x;
  const int qt = (int)gridDim.y - 1 - (int)blockIdx.y;   // LPT: heavy first
  const int b = bh >> 4, h = bh & 15;
  const int qw = qt * 128 + wave * 32;

  bf16x8 qf[2][2];
#pragma unroll
  for (int u = 0; u < 2; ++u) {
    const u16* Qb = Qh + ((size_t)bh * S + qw + u * 16 + r) * DH;
    qf[u][0] = *(const bf16x8*)(Qb + g * 8);
    qf[u][1] = *(const bf16x8*)(Qb + 32 + g * 8);
  }

  f32x4 acc[2][4] = {};
  float mrun[2][4], lrun[2][4];
#pragma unroll
  for (int u = 0; u < 2; ++u)
#pragma unroll
    for (int i = 0; i < 4; ++i) { mrun[u][i] = -INFINITY; lrun[u][i] = 0.f; }

  auto stage = [&](int buf, int kvt) {
    const int s0k = kvt * 64;
#pragma unroll
    for (int i = 0; i < 2; ++i) {
      int c = tid + i * 256;
      int row = c >> 3;
      int cc = (c & 7) ^ (row & 7);
      gload_lds16(Kh + ((size_t)bh * S + s0k + row) * DH + cc * 8, &sK[buf][0] + c * 8);
      gload_lds16(Vt + ((size_t)bh * DH + row) * S + s0k + cc * 8, &sV[buf][0] + c * 8);
    }
  };

  const int NT = 2 * (qt + 1);
  stage(0, 0);
  for (int kvt = 0; kvt < NT; ++kvt) {
    __syncthreads();
    if (kvt + 1 < NT) stage((kvt + 1) & 1, kvt + 1);
    const int cur = kvt & 1;
    const int s0 = kvt * 64;
    const bool pad = padflags[b * 16 + (s0 >> 6)] != 0;
    const u16* Kb = &sK[cur][0];
    const u16* Vb = &sV[cur][0];
    u16* Pw = &sP[wave][0];

#pragma unroll
    for (int u = 0; u < 2; ++u) {
      const int qg = qw + u * 16;
      if (s0 > qg + 15) continue;
      const bool diag = (s0 + 63 > qg);

      f32x4 sc[4] = {};
      __builtin_amdgcn_s_setprio(1);
#pragma unroll
      for (int ss = 0; ss < 4; ++ss) {
#pragma unroll
        for (int kc = 0; kc < 2; ++kc) {
          int krow = ss * 16 + r;
          int byteoff = krow * 128 + kc * 64 + g * 16;
          bf16x8 kf = *(const bf16x8*)((const char*)Kb + (byteoff ^ ((krow & 7) << 4)));
          sc[ss] = __builtin_amdgcn_mfma_f32_16x16x32_bf16(qf[u][kc], kf, sc[ss], 0, 0, 0);
        }
      }
      __builtin_amdgcn_s_setprio(0);

      float sv[4][4];
      float pmax[4] = {-INFINITY, -INFINITY, -INFINITY, -INFINITY};
#pragma unroll
      for (int ss = 0; ss < 4; ++ss) {
        float padd = 0.f;
        if (pad) {
          int s_g = s0 + ss * 16 + r;
          if (mask[(size_t)b * S + s_g]) padd = -INFINITY;
        }
#pragma unroll
        for (int reg = 0; reg < 4; ++reg) {
          float v = sc[ss][reg] + padd;
          if (diag) {
            int s_g = s0 + ss * 16 + r;
            int q_g = qg + g * 4 + reg;
            if (s_g > q_g) v = -INFINITY;
          }
          sv[ss][reg] = v;
          pmax[reg] = fmaxf(pmax[reg], v);
        }
      }

      float tm[4];
#pragma unroll
      for (int reg = 0; reg < 4; ++reg) tm[reg] = rowmax16(pmax[reg]);
      float dmax = fmaxf(fmaxf(tm[0] - mrun[u][0], tm[1] - mrun[u][1]),
                         fmaxf(tm[2] - mrun[u][2], tm[3] - mrun[u][3]));
      if (__any(dmax > DEFER_THR)) {
#pragma unroll
        for (int reg = 0; reg < 4; ++reg) {
          float newm = fmaxf(mrun[u][reg], tm[reg]);
          float alpha = (newm == -INFINITY) ? 1.f : exp2f(mrun[u][reg] - newm);
          mrun[u][reg] = newm;
          float rs = 0.f;
#pragma unroll
          for (int ss = 0; ss < 4; ++ss) {
            float p = (newm == -INFINITY) ? 0.f : exp2f(sv[ss][reg] - newm);
            sv[ss][reg] = p;
            rs += p;
          }
          rs = rowsum16(rs);
          lrun[u][reg] = lrun[u][reg] * alpha + rs;
#pragma unroll
          for (int df = 0; df < 4; ++df) acc[u][df][reg] *= alpha;
        }
      } else {
#pragma unroll
        for (int reg = 0; reg < 4; ++reg) {
          float m = mrun[u][reg];
          float rs = 0.f;
#pragma unroll
          for (int ss = 0; ss < 4; ++ss) {
            float p = (m == -INFINITY) ? 0.f : exp2f(sv[ss][reg] - m);
            sv[ss][reg] = p;
            rs += p;
          }
          rs = rowsum16(rs);
          lrun[u][reg] += rs;
        }
      }

#pragma unroll
      for (int ss = 0; ss < 4; ++ss) {
#pragma unroll
        for (int reg = 0; reg < 4; ++reg) {
          int qrow = g * 4 + reg;
          int byteoff = qrow * 128 + (ss * 16 + r) * 2;
          u32 bits = __builtin_bit_cast(u32, sv[ss][reg]);
          *(u16*)((char*)Pw + (byteoff ^ ((qrow & 7) << 4))) = (u16)(bits >> 16);
        }
      }

      __builtin_amdgcn_s_setprio(1);
#pragma unroll
      for (int sc2 = 0; sc2 < 2; ++sc2) {
        int pbyte = r * 128 + sc2 * 64 + g * 16;
        bf16x8 pf = *(const bf16x8*)((const char*)Pw + (pbyte ^ ((r & 7) << 4)));
#pragma unroll
        for (int df = 0; df < 4; ++df) {
          int vrow = df * 16 + r;
          int vbyte = vrow * 128 + sc2 * 64 + g * 16;
          bf16x8 vf = *(const bf16x8*)((const char*)Vb + (vbyte ^ ((vrow & 7) << 4)));
          acc[u][df] = __builtin_amdgcn_mfma_f32_16x16x32_bf16(pf, vf, acc[u][df], 0, 0, 0);
        }
      }
      __builtin_amdgcn_s_setprio(0);
    }
  }

#pragma unroll
  for (int u = 0; u < 2; ++u) {
#pragma unroll
    for (int reg = 0; reg < 4; ++reg) {
      float l = lrun[u][reg];
      float inv = (l > 0.f) ? 1.f / l : 0.f;
      int t = qw + u * 16 + g * 4 + reg;
#pragma unroll
      for (int df = 0; df < 4; ++df) {
        float vo = acc[u][df][reg] * inv;
        O[((size_t)b * 1024 + t) * 1024 + h * 64 + df * 16 + r] = f2bf(vo);
      }
    }
  }
}

// ---------- launch ----------

extern "C" void kernel_launch(void* const* d_in, const int* in_sizes, int n_in,
                              void* d_out, int out_size, void* d_ws, size_t ws_size,
                              hipStream_t stream) {
  const float* q  = (const float*)d_in[0];
  const float* k  = (const float*)d_in[1];
  const float* v  = (const float*)d_in[2];
  const unsigned char* mask = (const unsigned char*)d_in[3];
  const float* Wq = (const float*)d_in[4];
  const float* bq = (const float*)d_in[5];
  const float* Wk = (const float*)d_in[6];
  const float* bk = (const float*)d_in[7];
  const float* Wv = (const float*)d_in[8];
  const float* bv = (const float*)d_in[9];
  const float* Wo = (const float*)d_in[10];
  const float* bo = (const float*)d_in[11];

  const int M = 8192, N = 1024, K = 1024;
  const size_t MB = 1u << 20;
  char* ws = (char*)d_ws;

  u16* Aq   = (u16*)(ws);                 // 16MB, reused as AttO after QKV GEMM
  u16* Ak   = (u16*)(ws + 16 * MB);
  u16* Av   = (u16*)(ws + 32 * MB);
  u16* Qh   = (u16*)(ws + 48 * MB);
  u16* Kh   = (u16*)(ws + 64 * MB);
  u16* Vt   = (u16*)(ws + 80 * MB);
  u16* Wqb  = (u16*)(ws + 96 * MB);
  u16* Wkb  = Wqb + (1u << 20);
  u16* Wvb  = Wkb + (1u << 20);
  u16* Wob  = Wvb + (1u << 20);
  unsigned char* flags = (unsigned char*)(ws + 104 * MB);
  u16* AttO = Aq;

  cvt_all<<<dim3(1024, 7), 256, 0, stream>>>(
      (const float4*)q, (const float4*)k, (const float4*)v,
      (const float4*)Wq, (const float4*)Wk, (const float4*)Wv, (const float4*)Wo,
      (ushort4*)Aq, (ushort4*)Ak, (ushort4*)Av,
      (ushort4*)Wqb, (ushort4*)Wkb, (ushort4*)Wvb, (ushort4*)Wob,
      (M * K) / 4, (N * K) / 4);
  mask_flags<<<1, 128, 0, stream>>>(mask, flags);

  gemm_qkv<<<dim3(8, 64, 3), 256, 0, stream>>>(
      Aq, Ak, Av, Wqb, Wkb, Wvb, bq, bk, bv, Qh, Kh, Vt, M, N, K);

  attn_fwd<<<dim3(128, 8), 256, 0, stream>>>(Qh, Kh, Vt, mask, flags, AttO);

  gemm_o<<<dim3(8, 64), 256, 0, stream>>>(
      AttO, Wob, bo, (float*)d_out, M, N, K);
}